// Round 18
// baseline (186.147 us; speedup 1.0000x reference)
//
#include <hip/hip_runtime.h>
#include <hip/hip_bf16.h>

#define NTOT (4*256*256)      // 262144 feature rows
#define DIM 384
#define KCL 256               // clusters
#define BM 64                 // rows per block tile
#define TBS 256
#define GRID_MAIN (NTOT/BM)   // 4096 blocks
#define NT 12                 // K-steps of 32
#define EPS 1e-12f

// LDS: A double-buffer only. buf p at p*8192: hi +0, lo +4096. Total 16 KiB.
#define AB(p) ((p) * 8192)
#define SMEM_BYTES 16384

typedef __attribute__((ext_vector_type(8))) _Float16 f16x8;
typedef __attribute__((ext_vector_type(4))) float f32x4;

// ---------------------------------------------------------------------------
// Pre-pass: L2-normalize clusters; fp16 hi+lo residual in FRAGMENT ORDER:
// (j,d) -> ((((t*4+w)*4+n)*4+g)*16+nl)*8+d0  [proven R9-R17].
// ---------------------------------------------------------------------------
__global__ void prep_clusters(const float* __restrict__ cc,
                              _Float16* __restrict__ bh,
                              _Float16* __restrict__ bl) {
    int j = blockIdx.x, l = threadIdx.x;   // 256 blocks x 64 lanes
    float v[6]; float ssq = 0.f;
#pragma unroll
    for (int i = 0; i < 6; ++i) { v[i] = cc[j*DIM + l + 64*i]; ssq = fmaf(v[i], v[i], ssq); }
#pragma unroll
    for (int off = 32; off >= 1; off >>= 1) ssq += __shfl_xor(ssq, off);
    float inv = 1.f / fmaxf(sqrtf(ssq), EPS);
    const int w = j >> 6, n = (j >> 4) & 3, nl = j & 15;
#pragma unroll
    for (int i = 0; i < 6; ++i) {
        int d = l + 64 * i;
        float x = v[i] * inv;
        _Float16 h  = (_Float16)x;
        _Float16 lo = (_Float16)(x - (float)h);
        size_t idx = (size_t)((((((d >> 5)*4 + w)*4 + n)*4 + ((d >> 3) & 3))*16 + nl)*8
                              + (d & 7));
        bh[idx] = h;
        bl[idx] = lo;
    }
}

// ---------------------------------------------------------------------------
// Main: 3-pass split-fp16 MFMA GEMM, bit-identical numerics to R2-R6/R10-R17.
// R18 = R12 (182us best) with ALL s_setprio removed (T5 regime-gate: on
// barrier-lockstep structures setprio causes priority inversion at barriers,
// serializing co-resident blocks' chains instead of overlapping them; m190
// measured it as harmful on exactly this structure class).
// ---------------------------------------------------------------------------
__global__ __launch_bounds__(TBS, 3)
void kmeans_main(const float* __restrict__ A,    // [NTOT][384] f32
                 const float* __restrict__ W,    // [NTOT]
                 const _Float16* __restrict__ Bh,// fragment-order fp16 hi
                 const _Float16* __restrict__ Bl,// fragment-order fp16 lo
                 const int*   __restrict__ PA,   // [256]
                 float* __restrict__ out,        // [2*NTOT+1]
                 float* __restrict__ partial)    // [GRID_MAIN]
{
    __shared__ unsigned char smem[SMEM_BYTES];

    const int tid  = threadIdx.x;
    const int wv   = tid >> 6;        // wave -> cluster quarter [64wv, 64wv+64)
    const int lane = tid & 63;
    const int g    = lane >> 4;
    const int l15  = lane & 15;
    const int sw   = (l15 >> 1) & 3;  // A read-side swizzle (proven 0-conflict)
    const int row0 = blockIdx.x * BM;
    const int arow = tid >> 2, achk = tid & 3;
    const int awb  = (((arow << 2) + (achk ^ ((arow >> 1) & 3))) << 4);
    const int fa   = l15 * 64 + ((g ^ sw) << 4);      // A frag base (+m*1024)

    const float* ap = A + (size_t)(row0 + arow) * DIM + achk * 8;
    const unsigned char* bsh = (const unsigned char*)Bh + (size_t)(wv * 4) * 1024 + lane * 16;
    const unsigned char* bsl = (const unsigned char*)Bl + (size_t)(wv * 4) * 1024 + lane * 16;

    f32x4 acc[4][4];
#pragma unroll
    for (int m = 0; m < 4; ++m)
#pragma unroll
        for (int n = 0; n < 4; ++n) acc[m][n] = (f32x4){0.f, 0.f, 0.f, 0.f};
    float ssq = 0.f;

    f16x8  bfh[4], bfl[4];       // current B fragments (registers, single set)
    float4 sA[2][2];             // A f32 prefetch slots by tile parity

    auto LDA = [&](int s, int tt) {
        sA[s][0] = *(const float4*)(ap + tt * 32);
        sA[s][1] = *(const float4*)(ap + tt * 32 + 4);
    };
    auto LDBH = [&](int tt) {
#pragma unroll
        for (int n = 0; n < 4; ++n)
            bfh[n] = *(const f16x8*)(bsh + (size_t)(tt * 16 + n) * 1024);
    };
    auto LDBL = [&](int tt) {
#pragma unroll
        for (int n = 0; n < 4; ++n)
            bfl[n] = *(const f16x8*)(bsl + (size_t)(tt * 16 + n) * 1024);
    };
    // split f32 tile (slot s) -> hi/lo fp16, swizzled ds_write to buf p
    auto CVTW = [&](int s, int p) {
        float av[8] = {sA[s][0].x, sA[s][0].y, sA[s][0].z, sA[s][0].w,
                       sA[s][1].x, sA[s][1].y, sA[s][1].z, sA[s][1].w};
        f16x8 h8, l8;
#pragma unroll
        for (int e = 0; e < 8; ++e) {
            _Float16 hh = (_Float16)av[e];
            h8[e] = hh;
            l8[e] = (_Float16)(av[e] - (float)hh);
            ssq = fmaf(av[e], av[e], ssq);
        }
        *(f16x8*)(smem + AB(p) + awb) = h8;
        *(f16x8*)(smem + AB(p) + 4096 + awb) = l8;
    };

    // ---- prologue: tile0 -> buf0, B(0) -> regs, tile1 -> slot1 ----
    LDA(0, 0);
    LDBL(0); LDBH(0);
    LDA(1, 1);
    CVTW(0, 0);                  // compiler waits only the slot-0 loads
    asm volatile("s_waitcnt lgkmcnt(0)" ::: "memory");
    __builtin_amdgcn_s_barrier();

    // ---- main loop: fully unrolled; ONE lgkm-barrier per step ----
#pragma unroll
    for (int t = 0; t < NT; ++t) {
        if (t + 2 < NT) LDA((t + 2) & 1, t + 2);   // depth-2 A prefetch (HBM)

        f16x8 ahf[4], alf[4];
#pragma unroll
        for (int m = 0; m < 4; ++m) {
            ahf[m] = *(const f16x8*)(smem + AB(t & 1) + fa + m * 1024);
            alf[m] = *(const f16x8*)(smem + AB(t & 1) + 4096 + fa + m * 1024);
        }
        if (t + 1 < NT) CVTW((t + 1) & 1, (t + 1) & 1);  // publish A(t+1) -> other buf
        asm volatile("s_waitcnt lgkmcnt(0)" ::: "memory");
        __builtin_amdgcn_s_barrier();

        // 3 passes, order identical to R2-R6 (bit-identical accumulation).
        // NO setprio: let the CU scheduler interleave co-resident blocks.
#pragma unroll
        for (int m = 0; m < 4; ++m)
#pragma unroll
            for (int n = 0; n < 4; ++n)
                acc[m][n] = __builtin_amdgcn_mfma_f32_16x16x32_f16(ahf[m], bfh[n], acc[m][n], 0, 0, 0);
#pragma unroll
        for (int m = 0; m < 4; ++m)
#pragma unroll
            for (int n = 0; n < 4; ++n)
                acc[m][n] = __builtin_amdgcn_mfma_f32_16x16x32_f16(ahf[m], bfl[n], acc[m][n], 0, 0, 0);
        if (t + 1 < NT) LDBL(t + 1);               // bfl dead after pass 2
#pragma unroll
        for (int m = 0; m < 4; ++m)
#pragma unroll
            for (int n = 0; n < 4; ++n)
                acc[m][n] = __builtin_amdgcn_mfma_f32_16x16x32_f16(alf[m], bfh[n], acc[m][n], 0, 0, 0);
        if (t + 1 < NT) LDBH(t + 1);               // bfh dead after pass 3
    }
    __syncthreads();   // full drain before overlaying smem

    // ---- epilogue (overlay scratch on smem; R5/R10-proven logic) ----
    float* rowssq = (float*)smem;                 // 256 B
    float* wvalp  = (float*)(smem + 256);         // 1 KiB
    int*   wcolp  = (int*)(smem + 1280);          // 1 KiB

    ssq += __shfl_xor(ssq, 1);
    ssq += __shfl_xor(ssq, 2);
    if (achk == 0) rowssq[arow] = ssq;

    // per-row argmax. acc[m][n][j] = S[16m + 4g + j][64wv + 16n + l15]
#pragma unroll
    for (int m = 0; m < 4; ++m) {
#pragma unroll
        for (int j = 0; j < 4; ++j) {
            float best = acc[m][0][j];
            int   bc   = 64*wv + l15;
#pragma unroll
            for (int n = 1; n < 4; ++n) {
                float v = acc[m][n][j];
                int   c = 64*wv + 16*n + l15;
                if (v > best) { best = v; bc = c; }
            }
#pragma unroll
            for (int off = 1; off < 16; off <<= 1) {
                float ov = __shfl_xor(best, off);
                int   oc = __shfl_xor(bc, off);
                if (ov > best || (ov == best && oc < bc)) { best = ov; bc = oc; }
            }
            if (l15 == 0) {
                wvalp[wv * BM + 16*m + 4*g + j] = best;
                wcolp[wv * BM + 16*m + 4*g + j] = bc;
            }
        }
    }
    __syncthreads();

    if (tid < BM) {
        int r = tid;
        float best = wvalp[r]; int bc = wcolp[r];
#pragma unroll
        for (int w = 1; w < 4; ++w) {
            float ov = wvalp[w * BM + r]; int oc = wcolp[w * BM + r];
            if (ov > best || (ov == best && oc < bc)) { best = ov; bc = oc; }
        }
        float inv = 1.f / fmaxf(sqrtf(rowssq[r]), EPS);
        int gr = row0 + r;
        out[gr]        = (float)bc;
        out[NTOT + gr] = (float)PA[bc];
        float lsum = -(best * inv) * W[gr];
#pragma unroll
        for (int off = 32; off >= 1; off >>= 1) lsum += __shfl_xor(lsum, off);
        if (tid == 0) partial[blockIdx.x] = lsum;
    }
}

// ---------------------------------------------------------------------------
// Deterministic final loss reduction: 4096 partials -> mean
// ---------------------------------------------------------------------------
__global__ void loss_reduce(const float* __restrict__ partial, float* __restrict__ out_loss) {
    __shared__ float s[256];
    float v = 0.f;
    for (int i = threadIdx.x; i < GRID_MAIN; i += 256) v += partial[i];
    s[threadIdx.x] = v;
    __syncthreads();
    for (int off = 128; off >= 1; off >>= 1) {
        if ((int)threadIdx.x < off) s[threadIdx.x] += s[threadIdx.x + off];
        __syncthreads();
    }
    if (threadIdx.x == 0) out_loss[0] = s[0] * (1.0f / (float)NTOT);
}

extern "C" void kernel_launch(void* const* d_in, const int* in_sizes, int n_in,
                              void* d_out, int out_size, void* d_ws, size_t ws_size,
                              hipStream_t stream) {
    const float* features = (const float*)d_in[0];
    const float* weight   = (const float*)d_in[1];
    const float* cc       = (const float*)d_in[2];
    const int*   pa       = (const int*)d_in[3];
    float* out = (float*)d_out;

    _Float16* bh   = (_Float16*)d_ws;              // 192 KiB fragment-order hi
    _Float16* bl   = bh + KCL * DIM;               // 192 KiB fragment-order lo
    float* partial = (float*)(bl + KCL * DIM);     // 16 KiB

    hipLaunchKernelGGL(prep_clusters, dim3(KCL), dim3(64), 0, stream, cc, bh, bl);
    hipLaunchKernelGGL(kmeans_main, dim3(GRID_MAIN), dim3(TBS), 0, stream,
                       features, weight, bh, bl, pa, out, partial);
    hipLaunchKernelGGL(loss_reduce, dim3(1), dim3(256), 0, stream, partial, out + 2 * NTOT);
}